// Round 1
// baseline (778.117 us; speedup 1.0000x reference)
//
#include <hip/hip_runtime.h>

#define SPB 8  // samples per block

__device__ __forceinline__ float fast_tanh(float x) {
    // tanh(x) = 1 - 2/(exp(2x)+1); exp(2x) = exp2(x * 2*log2(e))
    float e = __builtin_amdgcn_exp2f(x * 2.8853900817779268f);
    return 1.0f - 2.0f * __builtin_amdgcn_rcpf(e + 1.0f);
}

__global__ __launch_bounds__(256) void lenet_fused(
    const float* __restrict__ x,
    const float* __restrict__ w1, const float* __restrict__ b1,
    const float* __restrict__ w2, const float* __restrict__ b2,
    const float* __restrict__ w3, const float* __restrict__ b3,
    const float* __restrict__ ow, const float* __restrict__ ob,
    float* __restrict__ out)
{
    __shared__ float xp[SPB][20][20];        // padded input, pad = -1
    __shared__ float a1[SPB][12][12][12];    // padded H1 activations, pad = -1
    __shared__ float a2[SPB][192];           // H2 activations (flat ch*16+pos)
    __shared__ float a3[SPB][30];            // H3 activations

    const int t = threadIdx.x;
    const int s0 = blockIdx.x * SPB;

    // ---- Phase 0: fill pad regions with -1 (whole buffers; interiors overwritten) ----
    {
        float4 m1 = make_float4(-1.f, -1.f, -1.f, -1.f);
        float4* xf = (float4*)&xp[0][0][0];
        #pragma unroll
        for (int i = 0; i < (SPB*400/4 + 255)/256; ++i) {
            int idx = t + i*256;
            if (idx < SPB*400/4) xf[idx] = m1;
        }
        float4* af = (float4*)&a1[0][0][0][0];
        for (int idx = t; idx < SPB*1728/4; idx += 256) af[idx] = m1;
    }
    __syncthreads();

    // ---- Phase 0b: load x into padded LDS (coalesced float4) ----
    {
        const float4* xg = (const float4*)(x + (size_t)s0 * 256);
        #pragma unroll
        for (int i = 0; i < SPB*64/256; ++i) {
            int idx = t + i*256;
            float4 v = xg[idx];
            int smp = idx >> 6, r = (idx >> 2) & 15, c4 = (idx & 3) * 4;
            xp[smp][2 + r][2 + c4 + 0] = v.x;
            xp[smp][2 + r][2 + c4 + 1] = v.y;
            xp[smp][2 + r][2 + c4 + 2] = v.z;
            xp[smp][2 + r][2 + c4 + 3] = v.w;
        }
    }
    __syncthreads();

    // ---- Phase 1: H1 conv 5x5 s2, 1->12ch, +bias, tanh ----
    // thread -> (sample = t>>5, positions idx and idx+32); loop channels.
    {
        const int s = t >> 5;
        const int idx = t & 31;
        float patch[2][25];
        #pragma unroll
        for (int pp = 0; pp < 2; ++pp) {
            int p = idx + pp*32;
            int oy = p >> 3, ox = p & 7;
            #pragma unroll
            for (int ky = 0; ky < 5; ++ky)
                #pragma unroll
                for (int kx = 0; kx < 5; ++kx)
                    patch[pp][ky*5+kx] = xp[s][2*oy+ky][2*ox+kx];
        }
        for (int ch = 0; ch < 12; ++ch) {   // rolled: keeps I$ small, weights scalar
            float acc0 = 0.f, acc1 = 0.f;
            #pragma unroll
            for (int k = 0; k < 25; ++k) {
                float w = w1[ch*25 + k];    // block-uniform -> s_load
                acc0 += w * patch[0][k];
                acc1 += w * patch[1][k];
            }
            {
                int p = idx, oy = p >> 3, ox = p & 7;
                a1[s][ch][2+oy][2+ox] = fast_tanh(acc0 + b1[ch*64 + p]);
            }
            {
                int p = idx + 32, oy = p >> 3, ox = p & 7;
                a1[s][ch][2+oy][2+ox] = fast_tanh(acc1 + b1[ch*64 + p]);
            }
        }
    }
    __syncthreads();

    // ---- Phase 2: H2 grouped convs 5x5 s2, +bias, tanh ----
    // wave-uniform oc-half so weight indices are scalar:
    // wave w: h = w&1 (oc h*6..h*6+5), samples (w>>1)*4 .. +3
    {
        const int wv = t >> 6, lane = t & 63;
        const int h = wv & 1;
        const int s = (wv >> 1) * 4 + (lane >> 4);
        const int p = lane & 15;
        const int oy = p >> 2, ox = p & 3;
        float acc[6] = {0.f,0.f,0.f,0.f,0.f,0.f};
        #pragma unroll
        for (int ic = 0; ic < 12; ++ic) {
            float patch[25];
            #pragma unroll
            for (int ky = 0; ky < 5; ++ky)
                #pragma unroll
                for (int kx = 0; kx < 5; ++kx)
                    patch[ky*5+kx] = a1[s][ic][2*oy+ky][2*ox+kx];
            if (h == 0) {
                // oc 0..3 (group 0: ic 0..7, icw=ic)
                if (ic < 8) {
                    #pragma unroll
                    for (int oc = 0; oc < 4; ++oc)
                        #pragma unroll
                        for (int k = 0; k < 25; ++k)
                            acc[oc] += w2[(oc*8 + ic)*25 + k] * patch[k];
                }
                // oc 4..5 (group 1: ic 4..11, icw=ic-4)
                if (ic >= 4) {
                    #pragma unroll
                    for (int i = 0; i < 2; ++i)
                        #pragma unroll
                        for (int k = 0; k < 25; ++k)
                            acc[4+i] += w2[((4+i)*8 + (ic-4))*25 + k] * patch[k];
                }
            } else {
                // oc 6..7 (group 1: ic 4..11, icw=ic-4)
                if (ic >= 4) {
                    #pragma unroll
                    for (int i = 0; i < 2; ++i)
                        #pragma unroll
                        for (int k = 0; k < 25; ++k)
                            acc[i] += w2[((6+i)*8 + (ic-4))*25 + k] * patch[k];
                }
                // oc 8..11 (group 2: ic 0..3 icw=ic; ic 8..11 icw=ic-4)
                if (ic < 4) {
                    #pragma unroll
                    for (int i = 0; i < 4; ++i)
                        #pragma unroll
                        for (int k = 0; k < 25; ++k)
                            acc[2+i] += w2[((8+i)*8 + ic)*25 + k] * patch[k];
                }
                if (ic >= 8) {
                    #pragma unroll
                    for (int i = 0; i < 4; ++i)
                        #pragma unroll
                        for (int k = 0; k < 25; ++k)
                            acc[2+i] += w2[((8+i)*8 + (ic-4))*25 + k] * patch[k];
                }
            }
        }
        #pragma unroll
        for (int i = 0; i < 6; ++i) {
            int oc = h*6 + i;
            a2[s][oc*16 + p] = fast_tanh(acc[i] + b2[oc*16 + p]);
        }
    }
    __syncthreads();

    // ---- Phase 3: H3 FC 192->30 + tanh ----
    if (t < SPB*30) {
        int s = t / 30, j = t - s*30;
        float acc = b3[j];
        const float* a = a2[s];
        #pragma unroll 8
        for (int k = 0; k < 192; ++k)
            acc += a[k] * w3[k*30 + j];
        a3[s][j] = fast_tanh(acc);
    }
    __syncthreads();

    // ---- Phase 4: out FC 30->10 + tanh, write global ----
    if (t < SPB*10) {
        int s = t / 10, j = t - s*10;
        float acc = ob[j];
        #pragma unroll
        for (int k = 0; k < 30; ++k)
            acc += a3[s][k] * ow[k*10 + j];
        out[(size_t)(s0 + s)*10 + j] = fast_tanh(acc);
    }
}

extern "C" void kernel_launch(void* const* d_in, const int* in_sizes, int n_in,
                              void* d_out, int out_size, void* d_ws, size_t ws_size,
                              hipStream_t stream) {
    const float* x  = (const float*)d_in[0];
    const float* w1 = (const float*)d_in[1];
    const float* b1 = (const float*)d_in[2];
    const float* w2 = (const float*)d_in[3];
    const float* b2 = (const float*)d_in[4];
    const float* w3 = (const float*)d_in[5];
    const float* b3 = (const float*)d_in[6];
    const float* ow = (const float*)d_in[7];
    const float* ob = (const float*)d_in[8];
    float* out = (float*)d_out;

    const int B = in_sizes[0] / 256;          // 65536 samples
    lenet_fused<<<dim3(B / SPB), dim3(256), 0, stream>>>(
        x, w1, b1, w2, b2, w3, b3, ow, ob, out);
}

// Round 2
// 581.196 us; speedup vs baseline: 1.3388x; 1.3388x over previous
//
#include <hip/hip_runtime.h>

#define SPB 8  // samples per block

// LDS geometry for padded H1 activations (pad value -1)
#define A1_ROW 13              // 12 padded cols + 1 (bank spread)
#define A1_IC  (12 * A1_ROW)   // 156 floats per input channel
#define A1_S   (12 * A1_IC + 8)// 1880 floats per sample; 1880 % 32 == 24
#define A2_S   200             // 192 used; 200 % 32 == 8

__device__ __forceinline__ float fast_tanh(float x) {
    // tanh(x) = 1 - 2/(exp(2x)+1); exp(2x) = exp2(x * 2*log2(e))
    float e = __builtin_amdgcn_exp2f(x * 2.8853900817779268f);
    return 1.0f - 2.0f * __builtin_amdgcn_rcpf(e + 1.0f);
}

// Dense zero-padded H2 weights: wd[ic][oc][k], 12*12*25 = 3600 floats.
__global__ __launch_bounds__(256) void prep_w2(const float* __restrict__ w2,
                                               float* __restrict__ wd) {
    int idx = blockIdx.x * 256 + threadIdx.x;
    if (idx >= 12 * 12 * 25) return;
    int k  = idx % 25;
    int oc = (idx / 25) % 12;
    int ic = idx / 300;
    int icw;
    if (oc < 4)      icw = (ic < 8) ? ic : -1;            // group 0: ic 0..7
    else if (oc < 8) icw = (ic >= 4) ? ic - 4 : -1;       // group 1: ic 4..11
    else             icw = (ic < 4) ? ic                  // group 2: ic 0..3, 8..11
                          : ((ic >= 8) ? ic - 4 : -1);
    wd[idx] = (icw >= 0) ? w2[(oc * 8 + icw) * 25 + k] : 0.0f;
}

__global__ __launch_bounds__(256) void lenet_fused(
    const float* __restrict__ x,
    const float* __restrict__ w1, const float* __restrict__ b1,
    const float* __restrict__ wd, const float* __restrict__ b2,
    const float* __restrict__ w3, const float* __restrict__ b3,
    const float* __restrict__ ow, const float* __restrict__ ob,
    float* __restrict__ out)
{
    __shared__ __attribute__((aligned(16))) float xp[SPB][20][20];   // padded x
    __shared__ __attribute__((aligned(16))) float a1[SPB * A1_S];    // padded H1 act
    __shared__ float a2[SPB][A2_S];
    __shared__ float a3[SPB][32];

    const int t = threadIdx.x;
    const int s0 = blockIdx.x * SPB;

    // ---- issue global x loads first (latency hides under pad-fill) ----
    const float4* xg = (const float4*)(x + (size_t)s0 * 256);
    float4 v0 = xg[t];
    float4 v1 = xg[t + 256];

    // ---- Phase 0: fill xp and a1 with -1 (interiors overwritten later) ----
    {
        float4 m1 = make_float4(-1.f, -1.f, -1.f, -1.f);
        float4* xf = (float4*)&xp[0][0][0];
        #pragma unroll
        for (int i = 0; i < SPB * 400 / 4 / 256 + 1; ++i) {
            int idx = t + i * 256;
            if (idx < SPB * 400 / 4) xf[idx] = m1;
        }
        float4* af = (float4*)&a1[0];
        for (int idx = t; idx < SPB * A1_S / 4; idx += 256) af[idx] = m1;
    }
    __syncthreads();

    // ---- Phase 0b: scatter x into padded LDS ----
    {
        int idx = t;                       // float4 index
        int smp = idx >> 6, r = (idx >> 2) & 15, c4 = (idx & 3) * 4;
        xp[smp][2 + r][2 + c4 + 0] = v0.x;
        xp[smp][2 + r][2 + c4 + 1] = v0.y;
        xp[smp][2 + r][2 + c4 + 2] = v0.z;
        xp[smp][2 + r][2 + c4 + 3] = v0.w;
        idx = t + 256;
        smp = idx >> 6; r = (idx >> 2) & 15; c4 = (idx & 3) * 4;
        xp[smp][2 + r][2 + c4 + 0] = v1.x;
        xp[smp][2 + r][2 + c4 + 1] = v1.y;
        xp[smp][2 + r][2 + c4 + 2] = v1.z;
        xp[smp][2 + r][2 + c4 + 3] = v1.w;
    }
    __syncthreads();

    // ---- Phase 1: H1 conv 5x5 s2, 1->12ch, +bias, tanh -> a1 (padded) ----
    // thread -> (sample = t>>5, 2 positions); channels rolled (scalar weights)
    {
        const int s = t >> 5;
        const int idx = t & 31;
        float* a1s = &a1[s * A1_S];
        for (int pp = 0; pp < 2; ++pp) {
            const int p = idx + pp * 32;
            const int oy = p >> 3, ox = p & 7;
            float patch[25];
            #pragma unroll
            for (int ky = 0; ky < 5; ++ky)
                #pragma unroll
                for (int kx = 0; kx < 5; ++kx)
                    patch[ky * 5 + kx] = xp[s][2 * oy + ky][2 * ox + kx];
            for (int ch = 0; ch < 12; ++ch) {
                float acc = 0.f;
                #pragma unroll
                for (int k = 0; k < 25; ++k)
                    acc += w1[ch * 25 + k] * patch[k];   // uniform -> s_load
                a1s[ch * A1_IC + (2 + oy) * A1_ROW + (2 + ox)] =
                    fast_tanh(acc + b1[ch * 64 + p]);
            }
        }
    }
    __syncthreads();

    // ---- Phase 2: H2 dense 12->12 conv (zero-padded weights), +bias, tanh ----
    // wave-uniform oc-half: waves {0,2}: oc 0..5, waves {1,3}: oc 6..11
    {
        const int wv = t >> 6, lane = t & 63;
        const int h6 = __builtin_amdgcn_readfirstlane((wv & 1) * 6);
        const int s = (wv >> 1) * 4 + (lane >> 4);
        const int p = lane & 15;
        const int oy = p >> 2, ox = p & 3;
        const float* a1s = &a1[s * A1_S + (2 * oy) * A1_ROW + 2 * ox];
        float acc[6] = {0.f, 0.f, 0.f, 0.f, 0.f, 0.f};
        for (int ic = 0; ic < 12; ++ic) {
            float patch[25];
            const float* r = a1s + ic * A1_IC;
            #pragma unroll
            for (int ky = 0; ky < 5; ++ky)
                #pragma unroll
                for (int kx = 0; kx < 5; ++kx)
                    patch[ky * 5 + kx] = r[ky * A1_ROW + kx];
            const float* wb = wd + (ic * 12 + h6) * 25;   // uniform -> s_load
            #pragma unroll
            for (int k = 0; k < 25; ++k) {
                float pk = patch[k];
                acc[0] += wb[k] * pk;
                acc[1] += wb[25 + k] * pk;
                acc[2] += wb[50 + k] * pk;
                acc[3] += wb[75 + k] * pk;
                acc[4] += wb[100 + k] * pk;
                acc[5] += wb[125 + k] * pk;
            }
        }
        #pragma unroll
        for (int i = 0; i < 6; ++i) {
            int oc = h6 + i;
            a2[s][oc * 16 + p] = fast_tanh(acc[i] + b2[oc * 16 + p]);
        }
    }
    __syncthreads();

    // ---- Phase 3: H3 FC 192->30 + tanh ----
    if (t < SPB * 30) {
        const int s = t / 30, j = t - s * 30;
        float acc = b3[j];
        const float* a = a2[s];               // broadcast reads
        const float* w = w3 + j;
        #pragma unroll 8
        for (int k = 0; k < 192; ++k)
            acc += a[k] * w[k * 30];
        a3[s][j] = fast_tanh(acc);
    }
    __syncthreads();

    // ---- Phase 4: out FC 30->10 + tanh ----
    if (t < SPB * 10) {
        const int s = t / 10, j = t - s * 10;
        float acc = ob[j];
        #pragma unroll
        for (int k = 0; k < 30; ++k)
            acc += a3[s][k] * ow[k * 10 + j];
        out[(size_t)(s0 + s) * 10 + j] = fast_tanh(acc);
    }
}

extern "C" void kernel_launch(void* const* d_in, const int* in_sizes, int n_in,
                              void* d_out, int out_size, void* d_ws, size_t ws_size,
                              hipStream_t stream) {
    const float* x  = (const float*)d_in[0];
    const float* w1 = (const float*)d_in[1];
    const float* b1 = (const float*)d_in[2];
    const float* w2 = (const float*)d_in[3];
    const float* b2 = (const float*)d_in[4];
    const float* w3 = (const float*)d_in[5];
    const float* b3 = (const float*)d_in[6];
    const float* ow = (const float*)d_in[7];
    const float* ob = (const float*)d_in[8];
    float* out = (float*)d_out;
    float* wd  = (float*)d_ws;   // 3600 floats dense H2 weights

    prep_w2<<<dim3((3600 + 255) / 256), dim3(256), 0, stream>>>(w2, wd);

    const int B = in_sizes[0] / 256;   // 65536 samples
    lenet_fused<<<dim3(B / SPB), dim3(256), 0, stream>>>(
        x, w1, b1, wd, b2, w3, b3, ow, ob, out);
}

// Round 5
// 338.739 us; speedup vs baseline: 2.2971x; 1.7158x over previous
//
#include <hip/hip_runtime.h>

typedef __attribute__((ext_vector_type(8))) short short8;   // 8 x bf16 bits
typedef __attribute__((ext_vector_type(4))) float f32x4;

#define SPB 8
// LDS element geometry (u16 units)
#define XP_S   408     // xp sample stride (20*20 + 8)
#define A1_ROW 13      // padded 12 cols + 1
#define A1_CH  156     // 12 rows * 13
#define A1_S   1880    // 12 ch * 156 + 8
#define A2_STR 10      // 8 samples + 2
#define A3_STR 10

__device__ __forceinline__ float fast_tanh(float x) {
    float e = __builtin_amdgcn_exp2f(x * 2.8853900817779268f);
    return 1.0f - 2.0f * __builtin_amdgcn_rcpf(e + 1.0f);
}
__device__ __forceinline__ unsigned short f2bf(float f) {
    unsigned u = __builtin_bit_cast(unsigned, f);
    return (unsigned short)((u + 0x7FFF + ((u >> 16) & 1)) >> 16);
}

// Fragment-pack layout in wf (short8 units):
// [0,64)=aw1   [64,832)=aw2[ic]   [832,1600)=aw3[rt*6+kt]   [1600,1664)=awo
__global__ __launch_bounds__(256, 2) void lenet_mfma(
    const float* __restrict__ x,
    const float* __restrict__ w1, const float* __restrict__ b1,
    const float* __restrict__ w2, const float* __restrict__ b2,
    const float* __restrict__ w3, const float* __restrict__ b3,
    const float* __restrict__ ow, const float* __restrict__ ob,
    float* __restrict__ out)
{
    __shared__ __attribute__((aligned(16))) unsigned short wf[13312];
    __shared__ __attribute__((aligned(16))) unsigned short xp[SPB * XP_S];
    __shared__ __attribute__((aligned(16))) unsigned short a1[SPB * A1_S];
    __shared__ unsigned short a2[192 * A2_STR + 16];   // [k=oc*16+p][sample]
    __shared__ unsigned short a3[32 * A3_STR + 16];    // [unit][sample]
    __shared__ float b1s[768], b2s[192], b3s[32], obs[16];

    const int t = threadIdx.x;
    const int lane = t & 63, wv = t >> 6;
    const int hi = lane >> 4, col = lane & 15;
    const int s0 = blockIdx.x * SPB;

    // issue global x loads first (latency hides under the weight build)
    const float4* xg = (const float4*)(x + (size_t)s0 * 256);
    float4 v0 = xg[2 * t], v1 = xg[2 * t + 1];

    // ---- Phase W: build all MFMA A-fragments in LDS (region bounds are
    // multiples of 256, so every iteration is branch-uniform) ----
    for (int i = 0; i < 52; ++i) {
        int idx = t + i * 256;
        float val = 0.f;
        if (idx < 512) {                      // H1: A[oc][kk] = w1[oc*25+kk]
            int l = idx >> 3, j = idx & 7;
            int oc = l & 15, kk = 8 * (l >> 4) + j;
            if (oc < 12 && kk < 25) val = w1[oc * 25 + kk];
        } else if (idx < 6656) {              // H2 dense: A[oc][ic,kk]
            int r = idx - 512, ic = r >> 9, l = (r >> 3) & 63, j = r & 7;
            int oc = l & 15, kk = 8 * (l >> 4) + j;
            if (oc < 12 && kk < 25) {
                int icw;
                if (oc < 4)      icw = (ic < 8) ? ic : -1;
                else if (oc < 8) icw = (ic >= 4) ? ic - 4 : -1;
                else             icw = (ic < 4) ? ic : ((ic >= 8) ? ic - 4 : -1);
                if (icw >= 0) val = w2[(oc * 8 + icw) * 25 + kk];
            }
        } else if (idx < 12800) {             // H3: A[unit][k] = w3[k*30+unit]
            int r = idx - 6656, fi = r >> 9, l = (r >> 3) & 63, j = r & 7;
            int rt = fi / 6, kt = fi - 6 * rt;
            int unit = rt * 16 + (l & 15), k = kt * 32 + 8 * (l >> 4) + j;
            if (unit < 30) val = w3[k * 30 + unit];
        } else {                              // out: A[row][k] = ow[k*10+row]
            int r = idx - 12800, l = r >> 3, j = r & 7;
            int row = l & 15, k = 8 * (l >> 4) + j;
            if (row < 10 && k < 30) val = ow[k * 10 + row];
        }
        wf[idx] = f2bf(val);
    }

    // ---- fills: pads to -1 (bf16), a2/a3 to 0, biases to LDS ----
    {
        unsigned* xpw = (unsigned*)xp;
        for (int i = t; i < SPB * XP_S / 2; i += 256) xpw[i] = 0xBF80BF80u;
        unsigned* a1w = (unsigned*)a1;
        for (int i = t; i < SPB * A1_S / 2; i += 256) a1w[i] = 0xBF80BF80u;
        unsigned* a2w = (unsigned*)a2;
        for (int i = t; i < (192 * A2_STR + 16) / 2; i += 256) a2w[i] = 0u;
        unsigned* a3w = (unsigned*)a3;
        for (int i = t; i < (32 * A3_STR + 16) / 2; i += 256) a3w[i] = 0u;
        for (int i = t; i < 768; i += 256) b1s[i] = b1[i];
        if (t < 192) b2s[t] = b2[t];
        if (t < 32)  b3s[t] = (t < 30) ? b3[t] : 0.f;
        if (t < 16)  obs[t] = (t < 10) ? ob[t] : 0.f;
    }
    __syncthreads();

    // per-lane gather offsets; pad k (>=25) clamps to 24 (weights there are 0)
    int kofs1[8], kofs2[8];
    #pragma unroll
    for (int j = 0; j < 8; ++j) {
        int kk = 8 * hi + j; int kc = kk > 24 ? 24 : kk;
        int ky = kc / 5, kx = kc - 5 * ky;
        kofs1[j] = ky * 20 + kx;
        kofs2[j] = ky * A1_ROW + kx;
    }
    const int q1 = 40 * (col >> 3) + 2 * (col & 7);   // H1 patch TL (padded): (4pt+2(col>>3), 2(col&7))
    const int q2 = 26 * (col >> 2) + 2 * (col & 3);   // H2 patch TL: (2(col>>2), 2(col&3))

    // ---- Phase 0b: scatter x into padded LDS (bf16) ----
    {
        int s = t >> 5, r = (t & 31) >> 1, c0 = (t & 1) * 8;
        int base = s * XP_S + (2 + r) * 20 + (2 + c0);   // even
        unsigned* dst = (unsigned*)xp + (base >> 1);
        dst[0] = (unsigned)f2bf(v0.x) | ((unsigned)f2bf(v0.y) << 16);
        dst[1] = (unsigned)f2bf(v0.z) | ((unsigned)f2bf(v0.w) << 16);
        dst[2] = (unsigned)f2bf(v1.x) | ((unsigned)f2bf(v1.y) << 16);
        dst[3] = (unsigned)f2bf(v1.z) | ((unsigned)f2bf(v1.w) << 16);
    }
    __syncthreads();

    const short8* wfv = (const short8*)wf;
    short8 aw1 = wfv[lane];
    short8 aw2[12];
    #pragma unroll
    for (int ic = 0; ic < 12; ++ic) aw2[ic] = wfv[64 + ic * 64 + lane];

    // ---- H1: wave wv -> samples 2wv, 2wv+1; 4 pos-tiles each ----
    #pragma unroll
    for (int si = 0; si < 2; ++si) {
        int s = 2 * wv + si;
        int sbase = s * XP_S + q1;
        #pragma unroll
        for (int pt = 0; pt < 4; ++pt) {
            int base = sbase + pt * 80;
            short8 b;
            #pragma unroll
            for (int j = 0; j < 8; ++j) b[j] = (short)xp[base + kofs1[j]];
            f32x4 acc = __builtin_amdgcn_mfma_f32_16x16x32_bf16(
                aw1, b, (f32x4){0.f, 0.f, 0.f, 0.f}, 0, 0, 0);
            int p = pt * 16 + col;
            int oy = p >> 3, ox = p & 7;
            int wbase = s * A1_S + (2 + oy) * A1_ROW + (2 + ox);
            #pragma unroll
            for (int jj = 0; jj < 4; ++jj) {
                int oc = hi * 4 + jj;
                if (oc < 12)
                    a1[wbase + oc * A1_CH] =
                        f2bf(fast_tanh(acc[jj] + b1s[oc * 64 + p]));
            }
        }
    }
    __syncthreads();

    // ---- H2: 12 chained MFMAs per sample (one ic per K-tile) ----
    #pragma unroll
    for (int si = 0; si < 2; ++si) {
        int s = 2 * wv + si;
        int sbase = s * A1_S + q2;
        f32x4 acc = {0.f, 0.f, 0.f, 0.f};
        #pragma unroll
        for (int ic = 0; ic < 12; ++ic) {
            int base = sbase + ic * A1_CH;
            short8 b;
            #pragma unroll
            for (int j = 0; j < 8; ++j) b[j] = (short)a1[base + kofs2[j]];
            acc = __builtin_amdgcn_mfma_f32_16x16x32_bf16(aw2[ic], b, acc, 0, 0, 0);
        }
        #pragma unroll
        for (int jj = 0; jj < 4; ++jj) {
            int oc = hi * 4 + jj;
            if (oc < 12)
                a2[(oc * 16 + col) * A2_STR + s] =
                    f2bf(fast_tanh(acc[jj] + b2s[oc * 16 + col]));
        }
    }
    __syncthreads();

    // ---- H3: waves 0,1 (row-tiles), N = 8 samples, K = 192 ----
    if (wv < 2) {
        int rt = wv;
        int colc = col < 8 ? col : 7;
        f32x4 acc = {0.f, 0.f, 0.f, 0.f};
        #pragma unroll
        for (int kt = 0; kt < 6; ++kt) {
            short8 a = wfv[832 + (rt * 6 + kt) * 64 + lane];
            short8 b;
            #pragma unroll
            for (int j = 0; j < 8; ++j) {
                int k = kt * 32 + 8 * hi + j;
                b[j] = (short)a2[k * A2_STR + colc];
            }
            acc = __builtin_amdgcn_mfma_f32_16x16x32_bf16(a, b, acc, 0, 0, 0);
        }
        #pragma unroll
        for (int jj = 0; jj < 4; ++jj) {
            int unit = rt * 16 + hi * 4 + jj;
            if (unit < 30 && col < 8)
                a3[unit * A3_STR + col] = f2bf(fast_tanh(acc[jj] + b3s[unit]));
        }
    }
    __syncthreads();

    // ---- out: wave 0, K = 30 (pad k clamped; weights there are 0) ----
    if (wv == 0) {
        int colc = col < 8 ? col : 7;
        short8 a = wfv[1600 + lane];
        short8 b;
        #pragma unroll
        for (int j = 0; j < 8; ++j) {
            int k = 8 * hi + j; if (k > 29) k = 29;
            b[j] = (short)a3[k * A3_STR + colc];
        }
        f32x4 acc = __builtin_amdgcn_mfma_f32_16x16x32_bf16(
            a, b, (f32x4){0.f, 0.f, 0.f, 0.f}, 0, 0, 0);
        #pragma unroll
        for (int jj = 0; jj < 4; ++jj) {
            int row = hi * 4 + jj;
            if (row < 10 && col < 8)
                out[(size_t)(s0 + col) * 10 + row] = fast_tanh(acc[jj] + obs[row]);
        }
    }
}

extern "C" void kernel_launch(void* const* d_in, const int* in_sizes, int n_in,
                              void* d_out, int out_size, void* d_ws, size_t ws_size,
                              hipStream_t stream) {
    const float* x  = (const float*)d_in[0];
    const float* w1 = (const float*)d_in[1];
    const float* b1 = (const float*)d_in[2];
    const float* w2 = (const float*)d_in[3];
    const float* b2 = (const float*)d_in[4];
    const float* w3 = (const float*)d_in[5];
    const float* b3 = (const float*)d_in[6];
    const float* ow = (const float*)d_in[7];
    const float* ob = (const float*)d_in[8];
    float* out = (float*)d_out;

    const int B = in_sizes[0] / 256;   // 65536 samples
    lenet_mfma<<<dim3(B / SPB), dim3(256), 0, stream>>>(
        x, w1, b1, w2, b2, w3, b3, ow, ob, out);
}

// Round 6
// 144.596 us; speedup vs baseline: 5.3813x; 2.3427x over previous
//
#include <hip/hip_runtime.h>

typedef __attribute__((ext_vector_type(8))) short short8;   // 8 x bf16 bits
typedef __attribute__((ext_vector_type(4))) float f32x4;

#define SPB 8    // samples per group
#define NG  8    // groups per block
// LDS element geometry (u16 units)
#define XP_S   408     // xp sample stride (20*20 + 8)
#define A1_ROW 13      // padded 12 cols + 1
#define A1_CH  156     // 12 rows * 13
#define A1_S   1880    // 12 ch * 156 + 8
#define A2_STR 10      // 8 samples + 2
#define A3_STR 10

__device__ __forceinline__ float fast_tanh(float x) {
    float e = __builtin_amdgcn_exp2f(x * 2.8853900817779268f);
    return 1.0f - 2.0f * __builtin_amdgcn_rcpf(e + 1.0f);
}
__device__ __forceinline__ unsigned short f2bf(float f) {
    unsigned u = __builtin_bit_cast(unsigned, f);
    return (unsigned short)((u + 0x7FFF + ((u >> 16) & 1)) >> 16);
}

// Fragment-pack layout in wf (short8 units):
// [0,64)=aw1   [64,832)=aw2[ic]   [832,1600)=aw3[rt*6+kt]   [1600,1664)=awo
__global__ __launch_bounds__(256, 2) void lenet_mfma(
    const float* __restrict__ x,
    const float* __restrict__ w1, const float* __restrict__ b1,
    const float* __restrict__ w2, const float* __restrict__ b2,
    const float* __restrict__ w3, const float* __restrict__ b3,
    const float* __restrict__ ow, const float* __restrict__ ob,
    float* __restrict__ out)
{
    __shared__ __attribute__((aligned(16))) unsigned short wf[13312];
    __shared__ __attribute__((aligned(16))) unsigned short xp[SPB * XP_S];
    __shared__ __attribute__((aligned(16))) unsigned short a1[SPB * A1_S];
    __shared__ unsigned short a2[192 * A2_STR + 16];   // [k=oc*16+p][sample]
    __shared__ unsigned short a3[32 * A3_STR + 16];    // [unit][sample]
    __shared__ float b1s[768], b2s[192], b3s[32], obs[16];

    const int t = threadIdx.x;
    const int lane = t & 63, wv = t >> 6;
    const int hi = lane >> 4, col = lane & 15;

    // issue group-0 x loads first (latency hides under the weight build)
    const float4* xg = (const float4*)(x + (size_t)blockIdx.x * NG * SPB * 256);
    float4 v0 = xg[2 * t], v1 = xg[2 * t + 1];

    // ---- Phase W (once per block): build MFMA A-fragments in LDS ----
    for (int i = 0; i < 52; ++i) {
        int idx = t + i * 256;
        float val = 0.f;
        if (idx < 512) {                      // H1: A[oc][kk] = w1[oc*25+kk]
            int l = idx >> 3, j = idx & 7;
            int oc = l & 15, kk = 8 * (l >> 4) + j;
            if (oc < 12 && kk < 25) val = w1[oc * 25 + kk];
        } else if (idx < 6656) {              // H2 dense: A[oc][ic,kk]
            int r = idx - 512, ic = r >> 9, l = (r >> 3) & 63, j = r & 7;
            int oc = l & 15, kk = 8 * (l >> 4) + j;
            if (oc < 12 && kk < 25) {
                int icw;
                if (oc < 4)      icw = (ic < 8) ? ic : -1;
                else if (oc < 8) icw = (ic >= 4) ? ic - 4 : -1;
                else             icw = (ic < 4) ? ic : ((ic >= 8) ? ic - 4 : -1);
                if (icw >= 0) val = w2[(oc * 8 + icw) * 25 + kk];
            }
        } else if (idx < 12800) {             // H3: A[unit][k] = w3[k*30+unit]
            int r = idx - 6656, fi = r >> 9, l = (r >> 3) & 63, j = r & 7;
            int rt = fi / 6, kt = fi - 6 * rt;
            int unit = rt * 16 + (l & 15), k = kt * 32 + 8 * (l >> 4) + j;
            if (unit < 30) val = w3[k * 30 + unit];
        } else {                              // out: A[row][k] = ow[k*10+row]
            int r = idx - 12800, l = r >> 3, j = r & 7;
            int row = l & 15, k = 8 * (l >> 4) + j;
            if (row < 10 && k < 30) val = ow[k * 10 + row];
        }
        wf[idx] = f2bf(val);
    }

    // ---- once per block: pads to -1 (bf16), a2/a3 zero, biases ----
    {
        unsigned* xpw = (unsigned*)xp;
        for (int i = t; i < SPB * XP_S / 2; i += 256) xpw[i] = 0xBF80BF80u;
        unsigned* a1w = (unsigned*)a1;
        for (int i = t; i < SPB * A1_S / 2; i += 256) a1w[i] = 0xBF80BF80u;
        unsigned* a2w = (unsigned*)a2;
        for (int i = t; i < (192 * A2_STR + 16) / 2; i += 256) a2w[i] = 0u;
        unsigned* a3w = (unsigned*)a3;
        for (int i = t; i < (32 * A3_STR + 16) / 2; i += 256) a3w[i] = 0u;
        for (int i = t; i < 768; i += 256) b1s[i] = b1[i];
        if (t < 192) b2s[t] = b2[t];
        if (t < 32)  b3s[t] = (t < 30) ? b3[t] : 0.f;
        if (t < 16)  obs[t] = (t < 10) ? ob[t] : 0.f;
    }
    __syncthreads();

    // per-lane gather offsets; pad k (>=25) clamps to 24 (weights there are 0)
    int kofs1[8], kofs2[8];
    #pragma unroll
    for (int j = 0; j < 8; ++j) {
        int kk = 8 * hi + j; int kc = kk > 24 ? 24 : kk;
        int ky = kc / 5, kx = kc - 5 * ky;
        kofs1[j] = ky * 20 + kx;
        kofs2[j] = ky * A1_ROW + kx;
    }
    const int q1 = 40 * (col >> 3) + 2 * (col & 7);   // H1 patch TL (padded)
    const int q2 = 26 * (col >> 2) + 2 * (col & 3);   // H2 patch TL (padded)

    const short8* wfv = (const short8*)wf;
    short8 aw1 = wfv[lane];
    short8 aw2[12];
    #pragma unroll
    for (int ic = 0; ic < 12; ++ic) aw2[ic] = wfv[64 + ic * 64 + lane];

    // ================= group loop =================
    #pragma unroll 1
    for (int g = 0; g < NG; ++g) {
        const int s0 = (blockIdx.x * NG + g) * SPB;

        // ---- scatter x into padded LDS (bf16); same-wave producer/consumer ----
        {
            int s = t >> 5, r = (t & 31) >> 1, c0 = (t & 1) * 8;
            int base = s * XP_S + (2 + r) * 20 + (2 + c0);   // even
            unsigned* dst = (unsigned*)xp + (base >> 1);
            dst[0] = (unsigned)f2bf(v0.x) | ((unsigned)f2bf(v0.y) << 16);
            dst[1] = (unsigned)f2bf(v0.z) | ((unsigned)f2bf(v0.w) << 16);
            dst[2] = (unsigned)f2bf(v1.x) | ((unsigned)f2bf(v1.y) << 16);
            dst[3] = (unsigned)f2bf(v1.z) | ((unsigned)f2bf(v1.w) << 16);
        }
        // prefetch next group's x (latency hides under H1..out)
        if (g + 1 < NG) {
            const float4* xgn = (const float4*)(x + (size_t)(blockIdx.x * NG + g + 1) * SPB * 256);
            v0 = xgn[2 * t]; v1 = xgn[2 * t + 1];
        }

        // ---- H1: wave wv -> samples 2wv, 2wv+1; 4 pos-tiles each ----
        #pragma unroll
        for (int si = 0; si < 2; ++si) {
            int s = 2 * wv + si;
            int sbase = s * XP_S + q1;
            #pragma unroll
            for (int pt = 0; pt < 4; ++pt) {
                int base = sbase + pt * 80;
                short8 b;
                #pragma unroll
                for (int j = 0; j < 8; ++j) b[j] = (short)xp[base + kofs1[j]];
                f32x4 acc = __builtin_amdgcn_mfma_f32_16x16x32_bf16(
                    aw1, b, (f32x4){0.f, 0.f, 0.f, 0.f}, 0, 0, 0);
                int p = pt * 16 + col;
                int oy = p >> 3, ox = p & 7;
                int wbase = s * A1_S + (2 + oy) * A1_ROW + (2 + ox);
                #pragma unroll
                for (int jj = 0; jj < 4; ++jj) {
                    int oc = hi * 4 + jj;
                    if (oc < 12)
                        a1[wbase + oc * A1_CH] =
                            f2bf(fast_tanh(acc[jj] + b1s[oc * 64 + p]));
                }
            }
        }
        // no barrier: H2 reads only this wave's samples

        // ---- H2: 12 chained MFMAs per sample (one ic per K-tile) ----
        #pragma unroll
        for (int si = 0; si < 2; ++si) {
            int s = 2 * wv + si;
            int sbase = s * A1_S + q2;
            f32x4 acc = {0.f, 0.f, 0.f, 0.f};
            #pragma unroll
            for (int ic = 0; ic < 12; ++ic) {
                int base = sbase + ic * A1_CH;
                short8 b;
                #pragma unroll
                for (int j = 0; j < 8; ++j) b[j] = (short)a1[base + kofs2[j]];
                acc = __builtin_amdgcn_mfma_f32_16x16x32_bf16(aw2[ic], b, acc, 0, 0, 0);
            }
            #pragma unroll
            for (int jj = 0; jj < 4; ++jj) {
                int oc = hi * 4 + jj;
                if (oc < 12)
                    a2[(oc * 16 + col) * A2_STR + s] =
                        f2bf(fast_tanh(acc[jj] + b2s[oc * 16 + col]));
            }
        }
        __syncthreads();   // B1: a2 consumed cross-wave

        // ---- H3: waves 0,1 (row-tiles), N = 8 samples, K = 192 ----
        if (wv < 2) {
            int rt = wv;
            int colc = col < 8 ? col : 7;
            f32x4 acc = {0.f, 0.f, 0.f, 0.f};
            #pragma unroll
            for (int kt = 0; kt < 6; ++kt) {
                short8 a = wfv[832 + (rt * 6 + kt) * 64 + lane];
                short8 b;
                #pragma unroll
                for (int j = 0; j < 8; ++j) {
                    int k = kt * 32 + 8 * hi + j;
                    b[j] = (short)a2[k * A2_STR + colc];
                }
                acc = __builtin_amdgcn_mfma_f32_16x16x32_bf16(a, b, acc, 0, 0, 0);
            }
            #pragma unroll
            for (int jj = 0; jj < 4; ++jj) {
                int unit = rt * 16 + hi * 4 + jj;
                if (unit < 30 && col < 8)
                    a3[unit * A3_STR + col] = f2bf(fast_tanh(acc[jj] + b3s[unit]));
            }
        }

        // ---- out: wave 0, K = 30 (needs a3 from waves 0,1) ----
        // note: a3 writes are wave 0/1; wave 0 must see wave 1's half -> barrier
        __syncthreads();   // a3 cross-wave + keeps waves 2,3 from racing ahead
        if (wv == 0) {
            int colc = col < 8 ? col : 7;
            short8 a = wfv[1600 + lane];
            short8 b;
            #pragma unroll
            for (int j = 0; j < 8; ++j) {
                int k = 8 * hi + j; if (k > 29) k = 29;
                b[j] = (short)a3[k * A3_STR + colc];
            }
            f32x4 acc = __builtin_amdgcn_mfma_f32_16x16x32_bf16(
                a, b, (f32x4){0.f, 0.f, 0.f, 0.f}, 0, 0, 0);
            #pragma unroll
            for (int jj = 0; jj < 4; ++jj) {
                int row = hi * 4 + jj;
                if (row < 10 && col < 8)
                    out[(size_t)(s0 + col) * 10 + row] = fast_tanh(acc[jj] + obs[row]);
            }
        }
        __syncthreads();   // B2: a2/a3 free before next group's H2/H3 writes
    }
}

extern "C" void kernel_launch(void* const* d_in, const int* in_sizes, int n_in,
                              void* d_out, int out_size, void* d_ws, size_t ws_size,
                              hipStream_t stream) {
    const float* x  = (const float*)d_in[0];
    const float* w1 = (const float*)d_in[1];
    const float* b1 = (const float*)d_in[2];
    const float* w2 = (const float*)d_in[3];
    const float* b2 = (const float*)d_in[4];
    const float* w3 = (const float*)d_in[5];
    const float* b3 = (const float*)d_in[6];
    const float* ow = (const float*)d_in[7];
    const float* ob = (const float*)d_in[8];
    float* out = (float*)d_out;

    const int B = in_sizes[0] / 256;   // 65536 samples
    lenet_mfma<<<dim3(B / (SPB * NG)), dim3(256), 0, stream>>>(
        x, w1, b1, w2, b2, w3, b3, ow, ob, out);
}